// Round 8
// baseline (340.757 us; speedup 1.0000x reference)
//
#include <hip/hip_runtime.h>

typedef unsigned short u16;
typedef unsigned int u32;
typedef __attribute__((ext_vector_type(8))) short short8v;   // 8 bf16 (4 VGPRs)
typedef __attribute__((ext_vector_type(4))) float f32x4;

// Problem constants
#define NPX   131072      // B*H*W = 32*64*64 pixels
#define CHN   128         // NUM_HIDDENS
#define HWN   4096        // H*W
#define EMB   64
#define NCODE 512

// ws layout (bytes) — total 565,248 (known-safe extent)
#define WS_HIST 0         // 512 * u32
#define WS_LOSS 2048      // 1 * f32
#define WS_CC   4096      // 512 * f32
#define WS_PWT  8192      // 128*64 f32 (pre_w transposed, 32 KB)
#define WS_IDX  40960     // 131072 * u16 (256 KB) -> ends 303104
#define WS_DT   303104    // 512*128 f32 decode table (256 KB) -> ends 565248

// out-region scratch (dead after vq_search; overwritten by vq_decode):
//   zh 32..16777248, zm 16777248..33554464, zl 33554464..50331680 (tiled splits)
//   ch 50855968..50921504, cm ..50987040, cl ..51052576 (tiled cb splits)
// MFMA-tiled layout (u16 units), elem (row r, col d):
//   idx = (r>>4)*1024 + (d>>3)*128 + (r&15)*8 + (d&7)

#define MFMA(a, b, c) __builtin_amdgcn_mfma_f32_16x16x32_bf16((a), (b), (c), 0, 0, 0)

// exact aligned-truncation 3-way split of fp32 into bf16 parts
#define SPLIT3(V, HH, MM, LL) {                          \
  u32 zb_ = __float_as_uint(V);                          \
  HH = zb_ >> 16;                                        \
  float fh_ = __uint_as_float(HH << 16);                 \
  float r1_ = __fsub_rn((V), fh_);                       \
  MM = __float_as_uint(r1_) >> 16;                       \
  float fm_ = __uint_as_float(MM << 16);                 \
  float r2_ = __fsub_rn(r1_, fm_);                       \
  LL = __float_as_uint(r2_) >> 16; }

__device__ __forceinline__ float rec3(u32 hb, u32 mb, u32 lb) {
  return __fadd_rn(__fadd_rn(__uint_as_float(hb), __uint_as_float(mb)),
                   __uint_as_float(lb));
}

// ===================== vq_init (round-7 verbatim, passed) =====================
__global__ __launch_bounds__(256) void vq_init(const float* __restrict__ preW,
                                               const float* __restrict__ cb,
                                               const float* __restrict__ postW,
                                               const float* __restrict__ postB,
                                               float* __restrict__ preWT,
                                               float* __restrict__ cc,
                                               u16* __restrict__ ch,
                                               u16* __restrict__ cm,
                                               u16* __restrict__ cl,
                                               float* __restrict__ DT,
                                               u32* __restrict__ wz) {
  int bid = blockIdx.x, tid = threadIdx.x;
  int idx = bid * 256 + tid;
  {   // DT entry
    int k = idx >> 7, o = idx & 127;
    const float* q = cb + k * EMB;
    const float* w = postW + o * EMB;
    float a0 = 0.f, a1 = 0.f, a2 = 0.f, a3 = 0.f;
#pragma unroll
    for (int dd = 0; dd < 64; dd += 4) {
      a0 = fmaf(q[dd + 0], w[dd + 0], a0);
      a1 = fmaf(q[dd + 1], w[dd + 1], a1);
      a2 = fmaf(q[dd + 2], w[dd + 2], a2);
      a3 = fmaf(q[dd + 3], w[dd + 3], a3);
    }
    DT[(size_t)k * 128 + o] = ((a0 + a1) + (a2 + a3)) + postB[o];
  }
  if (bid == 0) {
    for (int i = tid; i < CHN * EMB; i += 256) {
      int c = i >> 6, d = i & 63;
      preWT[i] = preW[d * CHN + c];   // preW is [64][128]
    }
  } else if (bid == 1) {
    for (int t = tid; t < NCODE; t += 256) {
      const float* row = cb + t * EMB;
      float r[8];
#pragma unroll
      for (int j = 0; j < 8; ++j) r[j] = __fmul_rn(row[j], row[j]);
#pragma unroll
      for (int b = 1; b < 8; ++b)
#pragma unroll
        for (int j = 0; j < 8; ++j)
          r[j] = __fadd_rn(r[j], __fmul_rn(row[b * 8 + j], row[b * 8 + j]));
      cc[t] = __fadd_rn(__fadd_rn(__fadd_rn(r[0], r[1]), __fadd_rn(r[2], r[3])),
                        __fadd_rn(__fadd_rn(r[4], r[5]), __fadd_rn(r[6], r[7])));
      int tile = t >> 4, rr = t & 15;
      for (int d = 0; d < EMB; ++d) {
        float v = row[d];
        u32 hh, mm, ll;
        SPLIT3(v, hh, mm, ll)
        size_t ti = (size_t)tile * 1024 + (size_t)(d >> 3) * 128 + rr * 8 + (d & 7);
        ch[ti] = (u16)hh;
        cm[ti] = (u16)mm;
        cl[ti] = (u16)ll;
      }
    }
  } else if (bid == 2) {
    for (int i = tid; i < 513; i += 256) wz[i] = 0;   // hist + lossAcc
  }
}

// ===================== vq_pre (round-7 verbatim, passed) =====================
__global__ __launch_bounds__(256) void vq_pre(const float* __restrict__ A,
                                              const float* __restrict__ preWT,
                                              const float* __restrict__ preB,
                                              u16* __restrict__ zh,
                                              u16* __restrict__ zm,
                                              u16* __restrict__ zl) {
  int bid = blockIdx.x;
  int ph = bid & 511, dh = bid >> 9;     // dh in {0..3}
  int d0 = dh << 4;
  int p = ph * 256 + threadIdx.x;
  int b = p >> 12, hw = p & 4095;
  const float* Ab = A + (size_t)b * CHN * HWN + hw;

  float z[16];
#pragma unroll
  for (int d = 0; d < 16; ++d) z[d] = 0.f;
  for (int c = 0; c < CHN; c += 4) {
    float a0 = Ab[(size_t)(c + 0) * HWN];
    float a1 = Ab[(size_t)(c + 1) * HWN];
    float a2 = Ab[(size_t)(c + 2) * HWN];
    float a3 = Ab[(size_t)(c + 3) * HWN];
    const float* w = preWT + c * EMB + d0;  // wave-uniform -> s_load
#pragma unroll
    for (int d = 0; d < 16; ++d) z[d] = __fadd_rn(z[d], __fmul_rn(a0, w[d]));
    w += EMB;
#pragma unroll
    for (int d = 0; d < 16; ++d) z[d] = __fadd_rn(z[d], __fmul_rn(a1, w[d]));
    w += EMB;
#pragma unroll
    for (int d = 0; d < 16; ++d) z[d] = __fadd_rn(z[d], __fmul_rn(a2, w[d]));
    w += EMB;
#pragma unroll
    for (int d = 0; d < 16; ++d) z[d] = __fadd_rn(z[d], __fmul_rn(a3, w[d]));
  }
#pragma unroll
  for (int d = 0; d < 16; ++d) z[d] = __fadd_rn(z[d], preB[d0 + d]);

  u32 hwd[8], mwd[8], lwd[8];
#pragma unroll
  for (int i = 0; i < 16; ++i) {
    u32 hh, mm, ll;
    SPLIT3(z[i], hh, mm, ll)
    int wdi = i >> 1;
    if ((i & 1) == 0) { hwd[wdi] = hh; mwd[wdi] = mm; lwd[wdi] = ll; }
    else { hwd[wdi] |= hh << 16; mwd[wdi] |= mm << 16; lwd[wdi] |= ll << 16; }
  }
  int tile = p >> 4, rr = p & 15;
  size_t base = (size_t)tile * 1024 + (size_t)(dh * 2) * 128 + rr * 8;
#pragma unroll
  for (int q = 0; q < 2; ++q) {
    size_t off = base + (size_t)q * 128;
    *(uint4*)(zh + off) = make_uint4(hwd[4*q], hwd[4*q+1], hwd[4*q+2], hwd[4*q+3]);
    *(uint4*)(zm + off) = make_uint4(mwd[4*q], mwd[4*q+1], mwd[4*q+2], mwd[4*q+3]);
    *(uint4*)(zl + off) = make_uint4(lwd[4*q], lwd[4*q+1], lwd[4*q+2], lwd[4*q+3]);
  }
}

// ===================== vq_search (round-6 structure + verified fusion) =======
// M=64/wave, grid 512, (256,2). 8-pass split MFMA k-loop verbatim from the
// 62-us round-6 kernel. Fused: exact zz (pairwise-8 chain) and exact loss
// (d-ascending fmaf chain) computed from LDS-staged rec3 z with a padded
// (stride-66) layout: float2 writes = 2-way bank alias (free), reads =
// broadcast x distinct banks (conflict-free). Staged 2 mt-tiles at a time.

#define LOADB(S, T) {                                                   \
  size_t ob_ = (size_t)((T) & 31) * 1024 + l8;                          \
  S##h0 = *(const short8v*)(ch + ob_); S##h1 = *(const short8v*)(ch + ob_ + 512); \
  S##m0 = *(const short8v*)(cm + ob_); S##m1 = *(const short8v*)(cm + ob_ + 512); \
  S##l0 = *(const short8v*)(cl + ob_); S##l1 = *(const short8v*)(cl + ob_ + 512); }

#define COMP(S, T) {                                                    \
  float ccv_ = scc[((T) << 4) + mcol];                                  \
  _Pragma("unroll")                                                     \
  for (int mt = 0; mt < 4; ++mt) {                                      \
    f32x4 acc = {0.f, 0.f, 0.f, 0.f};                                   \
    acc = MFMA(Ah[mt][0], S##h0, acc); acc = MFMA(Ah[mt][1], S##h1, acc); \
    acc = MFMA(Am[mt][0], S##h0, acc); acc = MFMA(Am[mt][1], S##h1, acc); \
    acc = MFMA(Ah[mt][0], S##m0, acc); acc = MFMA(Ah[mt][1], S##m1, acc); \
    acc = MFMA(Am[mt][0], S##m0, acc); acc = MFMA(Am[mt][1], S##m1, acc); \
    acc = MFMA(Al[mt][0], S##h0, acc); acc = MFMA(Al[mt][1], S##h1, acc); \
    acc = MFMA(Ah[mt][0], S##l0, acc); acc = MFMA(Ah[mt][1], S##l1, acc); \
    acc = MFMA(Al[mt][0], S##m0, acc); acc = MFMA(Al[mt][1], S##m1, acc); \
    acc = MFMA(Am[mt][0], S##l0, acc); acc = MFMA(Am[mt][1], S##l1, acc); \
    _Pragma("unroll")                                                   \
    for (int r = 0; r < 4; ++r) {                                       \
      float dist_ = __fadd_rn(__fadd_rn(zzr[mt][r], ccv_), -2.0f * acc[r]); \
      if (dist_ < best[mt][r]) { best[mt][r] = dist_; bidx[mt][r] = ((T) << 4) + mcol; } \
    } } }

// stage z rows of tiles (2*H, 2*H+1) into zs[wid] (wave-private slice)
#define STAGE_Z(H) {                                                    \
  _Pragma("unroll")                                                     \
  for (int mi = 0; mi < 2; ++mi) {                                      \
    int mt_ = 2 * (H) + mi;                                             \
    float* zr_ = &zs[wid][mi * 16 + mcol][0];                           \
    _Pragma("unroll")                                                   \
    for (int e = 0; e < 8; e += 2) {                                    \
      float2 v0_, v1_;                                                  \
      v0_.x = rec3(((u32)(u16)Ah[mt_][0][e]) << 16, ((u32)(u16)Am[mt_][0][e]) << 16, \
                   ((u32)(u16)Al[mt_][0][e]) << 16);                    \
      v0_.y = rec3(((u32)(u16)Ah[mt_][0][e+1]) << 16, ((u32)(u16)Am[mt_][0][e+1]) << 16, \
                   ((u32)(u16)Al[mt_][0][e+1]) << 16);                  \
      v1_.x = rec3(((u32)(u16)Ah[mt_][1][e]) << 16, ((u32)(u16)Am[mt_][1][e]) << 16, \
                   ((u32)(u16)Al[mt_][1][e]) << 16);                    \
      v1_.y = rec3(((u32)(u16)Ah[mt_][1][e+1]) << 16, ((u32)(u16)Am[mt_][1][e+1]) << 16, \
                   ((u32)(u16)Al[mt_][1][e+1]) << 16);                  \
      *(float2*)(zr_ + g * 8 + e) = v0_;                                \
      *(float2*)(zr_ + 32 + g * 8 + e) = v1_;                           \
    } } }

__global__ __launch_bounds__(256, 2) void vq_search(const u16* __restrict__ zh,
                                                    const u16* __restrict__ zm,
                                                    const u16* __restrict__ zl,
                                                    const u16* __restrict__ ch,
                                                    const u16* __restrict__ cm,
                                                    const u16* __restrict__ cl,
                                                    const float* __restrict__ cc,
                                                    const float* __restrict__ cb,
                                                    u16* __restrict__ wsIdx,
                                                    float* __restrict__ outIdx,
                                                    float* __restrict__ lossAcc,
                                                    unsigned int* __restrict__ hist) {
  __shared__ float scc[512];
  __shared__ float zs[4][32][66];   // pad 66: bank = row*2+d, 33.8 KB
  int tid = threadIdx.x;
  scc[tid] = cc[tid];
  scc[tid + 256] = cc[tid + 256];

  int lane = tid & 63, wid = tid >> 6;
  int Mbase = blockIdx.x * 256 + wid * 64;
  int mcol = lane & 15, g = lane >> 4;
  size_t l8 = (size_t)lane * 8;

  // A fragments: tiled lane-linear loads (coalesced 1KB/instr)
  short8v Ah[4][2], Am[4][2], Al[4][2];
#pragma unroll
  for (int mt = 0; mt < 4; ++mt) {
    size_t tz = (size_t)((Mbase >> 4) + mt) * 1024 + l8;
    Ah[mt][0] = *(const short8v*)(zh + tz); Ah[mt][1] = *(const short8v*)(zh + tz + 512);
    Am[mt][0] = *(const short8v*)(zm + tz); Am[mt][1] = *(const short8v*)(zm + tz + 512);
    Al[mt][0] = *(const short8v*)(zl + tz); Al[mt][1] = *(const short8v*)(zl + tz + 512);
  }
  __syncthreads();   // scc ready

  // zz: exact pairwise-8 chain (== old vq_zz), staged 2 tiles at a time
  float zzr[4][4];
#pragma unroll
  for (int h = 0; h < 2; ++h) {
    STAGE_Z(h)
    __syncthreads();
#pragma unroll
    for (int mi = 0; mi < 2; ++mi) {
      int mt = 2 * h + mi;
#pragma unroll
      for (int r = 0; r < 4; ++r) {
        const float* rowp = &zs[wid][mi * 16 + g * 4 + r][0];
        float rr[8];
#pragma unroll
        for (int bb = 0; bb < 8; ++bb)
#pragma unroll
          for (int j = 0; j < 8; ++j) {
            float v = rowp[bb * 8 + j];
            float sq = __fmul_rn(v, v);
            rr[j] = (bb == 0) ? sq : __fadd_rn(rr[j], sq);
          }
        zzr[mt][r] = __fadd_rn(
            __fadd_rn(__fadd_rn(rr[0], rr[1]), __fadd_rn(rr[2], rr[3])),
            __fadd_rn(__fadd_rn(rr[4], rr[5]), __fadd_rn(rr[6], rr[7])));
      }
    }
    if (h == 0) __syncthreads();
  }

  float best[4][4];
  int bidx[4][4];
#pragma unroll
  for (int mt = 0; mt < 4; ++mt)
#pragma unroll
    for (int r = 0; r < 4; ++r) { best[mt][r] = 3.4e38f; bidx[mt][r] = 0; }

  // k-loop: verbatim round-6 (62 us) PA/PB double buffer
  short8v PAh0, PAh1, PAm0, PAm1, PAl0, PAl1;
  short8v PBh0, PBh1, PBm0, PBm1, PBl0, PBl1;
  LOADB(PA, 0)
#pragma unroll 1
  for (int t2 = 0; t2 < 16; ++t2) {
    int t = t2 * 2;
    LOADB(PB, t + 1)
    COMP(PA, t)
    LOADB(PA, t + 2)   // wraps to tile 0 at the end (unused)
    COMP(PB, t + 1)
  }

  // cross-lane lexicographic (dist, k) min == first-min argmin;
  // butterfly leaves winner in ALL 16 lanes of the column group.
  int ixr[4][4];
#pragma unroll
  for (int mt = 0; mt < 4; ++mt)
#pragma unroll
    for (int r = 0; r < 4; ++r) {
      float v = best[mt][r];
      int ix = bidx[mt][r];
#pragma unroll
      for (int off = 1; off < 16; off <<= 1) {
        float ov = __shfl_xor(v, off, 64);
        int oi = __shfl_xor(ix, off, 64);
        if (ov < v || (ov == v && oi < ix)) { v = ov; ix = oi; }
      }
      ixr[mt][r] = ix;
      if (mcol == 0) {
        int row = Mbase + mt * 16 + g * 4 + r;
        wsIdx[row] = (u16)ix;
        outIdx[row] = (float)ix;
        atomicAdd(&hist[ix], 1u);
      }
    }

  // loss: exact per-row d-ascending fmaf chain (== old vq_combine).
  // LDS currently holds h=1 tiles (mt 2,3); do them first, restage mt 0,1.
  float ls = 0.f;
#pragma unroll
  for (int hh2 = 1; hh2 >= 0; --hh2) {
    if (hh2 == 0) { __syncthreads(); STAGE_Z(0) __syncthreads(); }
#pragma unroll
    for (int mi = 0; mi < 2; ++mi) {
      int mt = 2 * hh2 + mi;
#pragma unroll
      for (int r = 0; r < 4; ++r) {
        int krow = ixr[mt][r];
        const float4* q4 = (const float4*)(cb + (krow << 6));
        const float* zrow = &zs[wid][mi * 16 + g * 4 + r][0];
        float rls = 0.f;
#pragma unroll
        for (int bb = 0; bb < 8; ++bb) {
          float4 qa = q4[2 * bb], qb = q4[2 * bb + 1];
          float e;
          e = __fsub_rn(qa.x, zrow[8 * bb + 0]); rls = fmaf(e, e, rls);
          e = __fsub_rn(qa.y, zrow[8 * bb + 1]); rls = fmaf(e, e, rls);
          e = __fsub_rn(qa.z, zrow[8 * bb + 2]); rls = fmaf(e, e, rls);
          e = __fsub_rn(qa.w, zrow[8 * bb + 3]); rls = fmaf(e, e, rls);
          e = __fsub_rn(qb.x, zrow[8 * bb + 4]); rls = fmaf(e, e, rls);
          e = __fsub_rn(qb.y, zrow[8 * bb + 5]); rls = fmaf(e, e, rls);
          e = __fsub_rn(qb.z, zrow[8 * bb + 6]); rls = fmaf(e, e, rls);
          e = __fsub_rn(qb.w, zrow[8 * bb + 7]); rls = fmaf(e, e, rls);
        }
        ls += rls;
      }
    }
  }
  if (mcol != 0) ls = 0.f;   // one contribution per pixel row
#pragma unroll
  for (int off = 32; off; off >>= 1) ls += __shfl_xor(ls, off, 64);
  if (lane == 0) atomicAdd(lossAcc, ls);
}

// ===================== vq_decode (o-quarters, grid 2048) =====================
// Identical store addresses/values to the round-6/7 passing gather version.
__global__ __launch_bounds__(256) void vq_decode(const u16* __restrict__ wsIdx,
                                                 const float* __restrict__ DT,
                                                 float* __restrict__ dec) {
  int bid = blockIdx.x;
  int och = bid & 3, ph = bid >> 2;
  int p = ph * 256 + threadIdx.x;
  int b = p >> 12, hw = p & 4095;
  int k = wsIdx[p];
  const float4* Dk = (const float4*)(DT + (size_t)k * 128);   // L2-hot row
  float* out = dec + (size_t)b * CHN * HWN + hw;
#pragma unroll
  for (int oq = och * 8; oq < och * 8 + 8; ++oq) {
    float4 v = Dk[oq];
    out[(size_t)(4 * oq + 0) * HWN] = v.x;   // coalesced per o
    out[(size_t)(4 * oq + 1) * HWN] = v.y;
    out[(size_t)(4 * oq + 2) * HWN] = v.z;
    out[(size_t)(4 * oq + 3) * HWN] = v.w;
  }
}

// --- finalize: loss scalar + perplexity (unchanged)
__global__ __launch_bounds__(512) void vq_final(const unsigned int* __restrict__ hist,
                                                const float* __restrict__ lossAcc,
                                                float* __restrict__ outLoss,
                                                float* __restrict__ outPerp) {
  __shared__ float sred[8];
  int t = threadIdx.x;
  float c = (float)hist[t];
  float pavg = c * (1.0f / 131072.0f);
  float term = pavg * logf(pavg + 1e-10f);
#pragma unroll
  for (int off = 32; off; off >>= 1) term += __shfl_xor(term, off, 64);
  if ((t & 63) == 0) sred[t >> 6] = term;
  __syncthreads();
  if (t == 0) {
    float s = 0.f;
    for (int i = 0; i < 8; ++i) s += sred[i];
    *outPerp = expf(-s);
    *outLoss = 1.25f * (*lossAcc) * (1.0f / 8388608.0f);
  }
}

extern "C" void kernel_launch(void* const* d_in, const int* in_sizes, int n_in,
                              void* d_out, int out_size, void* d_ws, size_t ws_size,
                              hipStream_t stream) {
  const float* A     = (const float*)d_in[0];
  const float* preW  = (const float*)d_in[1];
  const float* preB  = (const float*)d_in[2];
  const float* cb    = (const float*)d_in[3];
  const float* postW = (const float*)d_in[4];
  const float* postB = (const float*)d_in[5];
  float* out = (float*)d_out;

  char* ws = (char*)d_ws;
  unsigned int* hist = (unsigned int*)(ws + WS_HIST);
  float* lossAcc = (float*)(ws + WS_LOSS);
  float* cc      = (float*)(ws + WS_CC);
  float* preWT   = (float*)(ws + WS_PWT);
  u16* wsIdx     = (u16*)(ws + WS_IDX);
  float* DT      = (float*)(ws + WS_DT);

  // scratch inside the decode-output region (overwritten by vq_decode last)
  char* outc = (char*)d_out;
  u16* zh = (u16*)(outc + 32);
  u16* zm = (u16*)(outc + 16777248);
  u16* zl = (u16*)(outc + 33554464);
  u16* ch = (u16*)(outc + 50855968);
  u16* cm = (u16*)(outc + 50921504);
  u16* cl = (u16*)(outc + 50987040);

  vq_init<<<256, 256, 0, stream>>>(preW, cb, postW, postB, preWT, cc,
                                   ch, cm, cl, DT, (u32*)ws);
  vq_pre<<<2048, 256, 0, stream>>>(A, preWT, preB, zh, zm, zl);
  vq_search<<<512, 256, 0, stream>>>(zh, zm, zl, ch, cm, cl, cc, cb,
                                     wsIdx, out + 16777218, lossAcc, hist);
  vq_decode<<<2048, 256, 0, stream>>>(wsIdx, DT, out + 1);
  vq_final<<<1, 512, 0, stream>>>(hist, lossAcc, out, out + 16777217);
}